// Round 1
// baseline (832.722 us; speedup 1.0000x reference)
//
#include <hip/hip_runtime.h>
#include <hip/hip_bf16.h>

// ---- problem constants ----
#define NN   40960
#define EE   327680
#define NN1  20480
#define EE2  163840
#define NN2  10240
#define BB   512
#define NCLS 10
#define KA   26           // 25 MLP rows + 1 bias row
#define AW   (KA*64)      // 1664 columns of A per node

#define ENCNEG 0x007FFFFFu

__device__ __forceinline__ unsigned enc_f(float f) {
    unsigned u = __float_as_uint(f);
    return (u & 0x80000000u) ? ~u : (u | 0x80000000u);
}
__device__ __forceinline__ float dec_f(unsigned u) {
    unsigned v = (u & 0x80000000u) ? (u & 0x7FFFFFFFu) : ~u;
    return __uint_as_float(v);
}
__device__ __forceinline__ float elu_f(float v) { return v > 0.f ? v : (expf(v) - 1.f); }

// ---- init enc/batch buffers ----
__global__ void init_enc(unsigned* x1pEnc, unsigned* x2pEnc, int* batch1, int* batch2, unsigned* mBits) {
    int i = blockIdx.x * 256 + threadIdx.x;
    if (i < NN1 * 32) x1pEnc[i] = ENCNEG;
    if (i < NN2 * 64) x2pEnc[i] = ENCNEG;
    if (i < NN1) batch1[i] = -1073741824;
    if (i < NN2) batch2[i] = -1073741824;
    if (i == 0) *mBits = 0u;
}

// ---- conv1: per-edge MLP + scatter-add ----
__global__ void conv1_edge(const float* __restrict__ x, const float* __restrict__ ea,
                           const int* __restrict__ ei,
                           const float* __restrict__ w1, const float* __restrict__ b1,
                           const float* __restrict__ w2, const float* __restrict__ b2,
                           float* aggr1, float* cnt1) {
    __shared__ float sw1[50], sb1[25], sw2[25 * 32], sb2[32];
    int t = threadIdx.x;
    for (int i = t; i < 50; i += 256) sw1[i] = w1[i];
    for (int i = t; i < 25; i += 256) sb1[i] = b1[i];
    for (int i = t; i < 800; i += 256) sw2[i] = w2[i];
    for (int i = t; i < 32; i += 256) sb2[i] = b2[i];
    __syncthreads();
    int e = blockIdx.x * 256 + t;
    if (e >= EE) return;
    int s = ei[e], d = ei[EE + e];
    float ax = ea[2 * e], ay = ea[2 * e + 1];
    float h1[25];
#pragma unroll
    for (int k = 0; k < 25; k++) {
        float v = ax * sw1[k] + ay * sw1[25 + k] + sb1[k];
        h1[k] = v > 0.f ? v : 0.f;
    }
    float xs = x[s];
    float* base = aggr1 + (size_t)d * 32;
#pragma unroll
    for (int j = 0; j < 32; j++) {
        float hj = sb2[j];
#pragma unroll
        for (int k = 0; k < 25; k++) hj += h1[k] * sw2[k * 32 + j];
        atomicAdd(base + j, xs * hj);
    }
    atomicAdd(cnt1 + d, 1.0f);
}

// ---- x1 = elu(x*root1 + aggr/cnt + bias) ----
__global__ void x1_kernel(const float* __restrict__ x, const float* __restrict__ aggr1,
                          const float* __restrict__ cnt1, const float* __restrict__ root1,
                          const float* __restrict__ bias1, float* x1) {
    int idx = blockIdx.x * 256 + threadIdx.x;
    if (idx >= NN * 32) return;
    int n = idx >> 5, j = idx & 31;
    float v = x[n] * root1[j] + aggr1[idx] / fmaxf(cnt1[n], 1.0f) + bias1[j];
    x1[idx] = elu_f(v);
}

// ---- pool1 scatter: max features / sum pos / count / max batch ----
__global__ void pool1_scatter(const float* __restrict__ x1, const float* __restrict__ pos,
                              const int* __restrict__ batch, const int* __restrict__ cluster1,
                              unsigned* x1pEnc, float* possum, float* ccnt, int* batch1) {
    int idx = blockIdx.x * 256 + threadIdx.x;
    if (idx >= NN * 32) return;
    int v = idx >> 5, j = idx & 31;
    int c = cluster1[v];
    atomicMax(x1pEnc + c * 32 + j, enc_f(x1[idx]));
    if (j == 0) {
        atomicAdd(possum + 2 * c, pos[2 * v]);
        atomicAdd(possum + 2 * c + 1, pos[2 * v + 1]);
        atomicAdd(ccnt + c, 1.0f);
        atomicMax(batch1 + c, batch[v]);
    }
}

__global__ void pool1_fin(const unsigned* __restrict__ x1pEnc, const float* __restrict__ possum,
                          const float* __restrict__ ccnt, float* x1p, float* pos1, int* batch1) {
    int idx = blockIdx.x * 256 + threadIdx.x;
    if (idx >= NN1 * 32) return;
    int c = idx >> 5, j = idx & 31;
    unsigned u = x1pEnc[idx];
    x1p[idx] = (u == ENCNEG) ? 0.f : dec_f(u);
    if (j == 0) {
        float cn = fmaxf(ccnt[c], 1.0f);
        pos1[2 * c] = possum[2 * c] / cn;
        pos1[2 * c + 1] = possum[2 * c + 1] / cn;
        int b = batch1[c];
        batch1[c] = b < 0 ? 0 : (b > BB - 1 ? BB - 1 : b);
    }
}

// ---- global max |cart| over pooled edges ----
__global__ void cartmax(const float* __restrict__ pos1, const int* __restrict__ ei2, unsigned* mBits) {
    int e = blockIdx.x * 256 + threadIdx.x;
    float m = 0.f;
    if (e < EE2) {
        int r = ei2[e], c = ei2[EE2 + e];
        m = fmaxf(fabsf(pos1[2 * r] - pos1[2 * c]), fabsf(pos1[2 * r + 1] - pos1[2 * c + 1]));
    }
    for (int off = 32; off; off >>= 1) m = fmaxf(m, __shfl_xor(m, off, 64));
    if ((threadIdx.x & 63) == 0) atomicMax(mBits, __float_as_uint(m));
}

// ---- A[n, k*64+o] = sum_i x1p[n,i] * Wext[k, i*64+o]  (k=25 is b2 row) ----
__global__ void a_gemm(const float* __restrict__ x1p, const float* __restrict__ w2,
                       const float* __restrict__ b2, __hip_bfloat16* A) {
    __shared__ float Xs[64][32];
    __shared__ float Ws[32][64];
    int t = threadIdx.x;
    int n0 = blockIdx.x * 64;
    int k = blockIdx.y;
    for (int i = t; i < 64 * 32; i += 256) Xs[i / 32][i % 32] = x1p[(size_t)n0 * 32 + i];
    const float* wrow = (k < 25) ? (w2 + (size_t)k * 2048) : b2;
    for (int i = t; i < 32 * 64; i += 256) Ws[i / 64][i % 64] = wrow[i];
    __syncthreads();
    int o = t % 64, r0 = t / 64;
    float acc[16];
#pragma unroll
    for (int m2 = 0; m2 < 16; m2++) acc[m2] = 0.f;
    for (int i = 0; i < 32; i++) {
        float w = Ws[i][o];
#pragma unroll
        for (int m2 = 0; m2 < 16; m2++) acc[m2] += Xs[r0 + 4 * m2][i] * w;
    }
#pragma unroll
    for (int m2 = 0; m2 < 16; m2++) {
        int n = n0 + r0 + 4 * m2;
        A[(size_t)n * AW + k * 64 + o] = __float2bfloat16(acc[m2]);
    }
}

// ---- conv2 edge: one wave per edge; msg = r_e @ A[src]; scatter-add ----
__global__ void conv2_edge(const __hip_bfloat16* __restrict__ A, const float* __restrict__ pos1,
                           const int* __restrict__ ei2, const float* __restrict__ w1,
                           const float* __restrict__ b1, const unsigned* __restrict__ mBits,
                           float* aggr2, float* cnt2) {
    int t = threadIdx.x;
    int lane = t & 63;
    int e = blockIdx.x * 4 + (t >> 6);
    int s = ei2[e], d = ei2[EE2 + e];
    float m = __uint_as_float(*mBits);
    float inv = 0.5f / m;
    float cx = (pos1[2 * s] - pos1[2 * d]) * inv + 0.5f;
    float cy = (pos1[2 * s + 1] - pos1[2 * d + 1]) * inv + 0.5f;
    float r = 0.f;
    if (lane < 25) {
        float v = cx * w1[lane] + cy * w1[25 + lane] + b1[lane];
        r = v > 0.f ? v : 0.f;
    } else if (lane == 25) {
        r = 1.f;
    }
    const __hip_bfloat16* Ab = A + (size_t)s * AW + lane;
    float msg = 0.f;
#pragma unroll
    for (int k = 0; k < KA; k++) {
        float rk = __shfl(r, k, 64);
        msg += rk * __bfloat162float(Ab[k * 64]);
    }
    atomicAdd(aggr2 + (size_t)d * 64 + lane, msg);
    if (lane == 0) atomicAdd(cnt2 + d, 1.0f);
}

// ---- x2 = elu(x1p@root2 + aggr2/cnt2 + bias2) ----
__global__ void x2_kernel(const float* __restrict__ x1p, const float* __restrict__ aggr2,
                          const float* __restrict__ cnt2, const float* __restrict__ root2,
                          const float* __restrict__ bias2, float* x2) {
    __shared__ float R[32 * 64];
    int t = threadIdx.x;
    for (int i = t; i < 2048; i += 256) R[i] = root2[i];
    __syncthreads();
    int idx = blockIdx.x * 256 + t;
    if (idx >= NN1 * 64) return;
    int n = idx >> 6, o = idx & 63;
    float acc = bias2[o];
    const float* xr = x1p + (size_t)n * 32;
#pragma unroll
    for (int i = 0; i < 32; i++) acc += xr[i] * R[i * 64 + o];
    acc += aggr2[idx] / fmaxf(cnt2[n], 1.0f);
    x2[idx] = elu_f(acc);
}

// ---- pool2 scatter ----
__global__ void pool2_scatter(const float* __restrict__ x2, const int* __restrict__ cluster2,
                              const int* __restrict__ batch1, unsigned* x2pEnc, int* batch2) {
    int idx = blockIdx.x * 256 + threadIdx.x;
    if (idx >= NN1 * 64) return;
    int n = idx >> 6, o = idx & 63;
    int c = cluster2[n];
    atomicMax(x2pEnc + c * 64 + o, enc_f(x2[idx]));
    if (o == 0) atomicMax(batch2 + c, batch1[n]);
}

// ---- pool2 finalize + global mean scatter ----
__global__ void pool2_fin(const unsigned* __restrict__ x2pEnc, const int* __restrict__ batch2,
                          float* xgsum, float* gcnt) {
    int idx = blockIdx.x * 256 + threadIdx.x;
    if (idx >= NN2 * 64) return;
    int n2 = idx >> 6, o = idx & 63;
    unsigned u = x2pEnc[idx];
    float v = (u == ENCNEG) ? 0.f : dec_f(u);
    int b = batch2[n2];
    b = b < 0 ? 0 : (b > BB - 1 ? BB - 1 : b);
    atomicAdd(xgsum + (size_t)b * 64 + o, v);
    if (o == 0) atomicAdd(gcnt + b, 1.0f);
}

// ---- head: mean -> fc1+elu -> fc2 -> log_softmax ----
__global__ void head_kernel(const float* __restrict__ xgsum, const float* __restrict__ gcnt,
                            const float* __restrict__ fc1w, const float* __restrict__ fc1b,
                            const float* __restrict__ fc2w, const float* __restrict__ fc2b,
                            float* out) {
    __shared__ float xg[64];
    __shared__ float h[128];
    __shared__ float lg[NCLS];
    __shared__ float red[2];
    int b = blockIdx.x;
    int t = threadIdx.x;
    if (t < 64) xg[t] = xgsum[(size_t)b * 64 + t] / fmaxf(gcnt[b], 1.0f);
    __syncthreads();
    float acc = fc1b[t];
    for (int i = 0; i < 64; i++) acc += xg[i] * fc1w[i * 128 + t];
    h[t] = elu_f(acc);
    __syncthreads();
    if (t < NCLS) {
        float a = fc2b[t];
        for (int j = 0; j < 128; j++) a += h[j] * fc2w[j * NCLS + t];
        lg[t] = a;
    }
    __syncthreads();
    if (t == 0) {
        float mx = lg[0];
        for (int i = 1; i < NCLS; i++) mx = fmaxf(mx, lg[i]);
        float se = 0.f;
        for (int i = 0; i < NCLS; i++) se += expf(lg[i] - mx);
        red[0] = mx;
        red[1] = logf(se);
    }
    __syncthreads();
    if (t < NCLS) out[(size_t)b * NCLS + t] = lg[t] - red[0] - red[1];
}

extern "C" void kernel_launch(void* const* d_in, const int* in_sizes, int n_in,
                              void* d_out, int out_size, void* d_ws, size_t ws_size,
                              hipStream_t stream) {
    const float* x = (const float*)d_in[0];
    const float* pos = (const float*)d_in[1];
    const float* edge_attr = (const float*)d_in[2];
    const int* ei = (const int*)d_in[3];
    const int* batch = (const int*)d_in[4];
    const int* cluster1 = (const int*)d_in[5];
    const int* ei2 = (const int*)d_in[6];
    const int* cluster2 = (const int*)d_in[7];
    const float* nn1_w1 = (const float*)d_in[8];
    const float* nn1_b1 = (const float*)d_in[9];
    const float* nn1_w2 = (const float*)d_in[10];
    const float* nn1_b2 = (const float*)d_in[11];
    const float* root1 = (const float*)d_in[12];
    const float* bias1 = (const float*)d_in[13];
    const float* nn2_w1 = (const float*)d_in[14];
    const float* nn2_b1 = (const float*)d_in[15];
    const float* nn2_w2 = (const float*)d_in[16];
    const float* nn2_b2 = (const float*)d_in[17];
    const float* root2 = (const float*)d_in[18];
    const float* bias2 = (const float*)d_in[19];
    const float* fc1w = (const float*)d_in[20];
    const float* fc1b = (const float*)d_in[21];
    const float* fc2w = (const float*)d_in[22];
    const float* fc2b = (const float*)d_in[23];

    float* ws = (float*)d_ws;
    // ---- workspace layout (float units) ----
    constexpr size_t OFF_AGGR1 = 0;                            // NN*32
    constexpr size_t OFF_CNT1 = OFF_AGGR1 + (size_t)NN * 32;   // NN
    constexpr size_t OFF_POSSUM = OFF_CNT1 + NN;               // NN1*2
    constexpr size_t OFF_CCNT = OFF_POSSUM + (size_t)NN1 * 2;  // NN1
    constexpr size_t OFF_AGGR2 = OFF_CCNT + NN1;               // NN1*64
    constexpr size_t OFF_CNT2 = OFF_AGGR2 + (size_t)NN1 * 64;  // NN1
    constexpr size_t OFF_XGSUM = OFF_CNT2 + NN1;               // BB*64
    constexpr size_t OFF_GCNT = OFF_XGSUM + (size_t)BB * 64;   // BB
    constexpr size_t ZTOT = OFF_GCNT + BB;                     // end of zero region
    constexpr size_t OFF_X1PENC = ZTOT;                        // NN1*32 (uint)
    constexpr size_t OFF_X2PENC = OFF_X1PENC + (size_t)NN1 * 32;  // NN2*64 (uint)
    constexpr size_t OFF_BATCH1 = OFF_X2PENC + (size_t)NN2 * 64;  // NN1 (int)
    constexpr size_t OFF_BATCH2 = OFF_BATCH1 + NN1;               // NN2 (int)
    constexpr size_t OFF_MBITS = OFF_BATCH2 + NN2;                // 1 (uint)
    constexpr size_t OFF_X1 = OFF_MBITS + 4;                      // NN*32
    constexpr size_t OFF_X1P = OFF_X1 + (size_t)NN * 32;          // NN1*32
    constexpr size_t OFF_POS1 = OFF_X1P + (size_t)NN1 * 32;       // NN1*2
    constexpr size_t OFF_X2 = OFF_POS1 + (size_t)NN1 * 2;         // NN1*64
    constexpr size_t OFF_A = OFF_X2 + (size_t)NN1 * 64;           // NN1*AW bf16 = NN1*AW/2 floats

    float* aggr1 = ws + OFF_AGGR1;
    float* cnt1 = ws + OFF_CNT1;
    float* possum = ws + OFF_POSSUM;
    float* ccnt = ws + OFF_CCNT;
    float* aggr2 = ws + OFF_AGGR2;
    float* cnt2 = ws + OFF_CNT2;
    float* xgsum = ws + OFF_XGSUM;
    float* gcnt = ws + OFF_GCNT;
    unsigned* x1pEnc = (unsigned*)(ws + OFF_X1PENC);
    unsigned* x2pEnc = (unsigned*)(ws + OFF_X2PENC);
    int* batch1 = (int*)(ws + OFF_BATCH1);
    int* batch2 = (int*)(ws + OFF_BATCH2);
    unsigned* mBits = (unsigned*)(ws + OFF_MBITS);
    float* x1 = ws + OFF_X1;
    float* x1p = ws + OFF_X1P;
    float* pos1 = ws + OFF_POS1;
    float* x2 = ws + OFF_X2;
    __hip_bfloat16* A = (__hip_bfloat16*)(ws + OFF_A);

    hipMemsetAsync(d_ws, 0, ZTOT * sizeof(float), stream);
    init_enc<<<2560, 256, 0, stream>>>(x1pEnc, x2pEnc, batch1, batch2, mBits);
    conv1_edge<<<EE / 256, 256, 0, stream>>>(x, edge_attr, ei, nn1_w1, nn1_b1, nn1_w2, nn1_b2,
                                             aggr1, cnt1);
    x1_kernel<<<NN * 32 / 256, 256, 0, stream>>>(x, aggr1, cnt1, root1, bias1, x1);
    pool1_scatter<<<NN * 32 / 256, 256, 0, stream>>>(x1, pos, batch, cluster1, x1pEnc, possum,
                                                     ccnt, batch1);
    pool1_fin<<<NN1 * 32 / 256, 256, 0, stream>>>(x1pEnc, possum, ccnt, x1p, pos1, batch1);
    cartmax<<<EE2 / 256, 256, 0, stream>>>(pos1, ei2, mBits);
    a_gemm<<<dim3(NN1 / 64, KA), 256, 0, stream>>>(x1p, nn2_w2, nn2_b2, A);
    conv2_edge<<<EE2 / 4, 256, 0, stream>>>(A, pos1, ei2, nn2_w1, nn2_b1, mBits, aggr2, cnt2);
    x2_kernel<<<NN1 * 64 / 256, 256, 0, stream>>>(x1p, aggr2, cnt2, root2, bias2, x2);
    pool2_scatter<<<NN1 * 64 / 256, 256, 0, stream>>>(x2, cluster2, batch1, x2pEnc, batch2);
    pool2_fin<<<NN2 * 64 / 256, 256, 0, stream>>>(x2pEnc, batch2, xgsum, gcnt);
    head_kernel<<<BB, 128, 0, stream>>>(xgsum, gcnt, fc1w, fc1b, fc2w, fc2b, (float*)d_out);
}

// Round 2
// 562.208 us; speedup vs baseline: 1.4812x; 1.4812x over previous
//
#include <hip/hip_runtime.h>
#include <hip/hip_bf16.h>

// ---- problem constants ----
#define NN   40960
#define EE   327680
#define NN1  20480
#define EE2  163840
#define NN2  10240
#define BB   512
#define NCLS 10
#define KA   26           // 25 MLP rows + 1 bias row
#define AW   (KA*64)      // 1664 columns of A per node

#define ENCNEG 0x007FFFFFu

__device__ __forceinline__ unsigned enc_f(float f) {
    unsigned u = __float_as_uint(f);
    return (u & 0x80000000u) ? ~u : (u | 0x80000000u);
}
__device__ __forceinline__ float dec_f(unsigned u) {
    unsigned v = (u & 0x80000000u) ? (u & 0x7FFFFFFFu) : ~u;
    return __uint_as_float(v);
}
__device__ __forceinline__ float elu_f(float v) { return v > 0.f ? v : (expf(v) - 1.f); }

// ---- init enc/batch buffers ----
__global__ void init_enc(unsigned* x1pEnc, unsigned* x2pEnc, int* batch1, int* batch2, unsigned* mBits) {
    int i = blockIdx.x * 256 + threadIdx.x;
    if (i < NN1 * 32) x1pEnc[i] = ENCNEG;
    if (i < NN2 * 64) x2pEnc[i] = ENCNEG;
    if (i < NN1) batch1[i] = -1073741824;
    if (i < NN2) batch2[i] = -1073741824;
    if (i == 0) *mBits = 0u;
}

// ---- CSR build: degree count for both graphs ----
__global__ void deg_count(const int* __restrict__ ei, const int* __restrict__ ei2,
                          int* deg1, int* deg2) {
    int i = blockIdx.x * 256 + threadIdx.x;
    if (i < EE) atomicAdd(deg1 + ei[EE + i], 1);
    if (i < EE2) atomicAdd(deg2 + ei2[EE2 + i], 1);
}

// ---- two exclusive scans (block 0: graph1, block 1: graph2) ----
__global__ void scan_two(const int* __restrict__ deg1, const int* __restrict__ deg2,
                         int* rowptr1, int* rowptr2, int* cur1, int* cur2) {
    __shared__ int part[1024];
    const int* deg;
    int *rp, *cur, n;
    if (blockIdx.x == 0) { deg = deg1; rp = rowptr1; cur = cur1; n = NN; }
    else                 { deg = deg2; rp = rowptr2; cur = cur2; n = NN1; }
    int t = threadIdx.x;
    int chunk = (n + 1023) / 1024;
    int base = t * chunk;
    int s = 0;
    for (int i = 0; i < chunk; i++) { int idx = base + i; if (idx < n) s += deg[idx]; }
    part[t] = s;
    __syncthreads();
    for (int off = 1; off < 1024; off <<= 1) {
        int u = (t >= off) ? part[t - off] : 0;
        __syncthreads();
        part[t] += u;
        __syncthreads();
    }
    int run = part[t] - s;  // exclusive prefix for this thread's chunk
    for (int i = 0; i < chunk; i++) {
        int idx = base + i;
        if (idx < n) { rp[idx] = run; cur[idx] = run; run += deg[idx]; }
    }
    if (t == 1023) rp[n] = part[1023];
}

// ---- CSR fill ----
__global__ void fill_csr(const int* __restrict__ ei, const int* __restrict__ ei2,
                         int* cur1, int* cur2, int* eidx1, int* eidx2) {
    int i = blockIdx.x * 256 + threadIdx.x;
    if (i < EE) { int d = ei[EE + i]; int p = atomicAdd(cur1 + d, 1); eidx1[p] = i; }
    if (i < EE2) { int d = ei2[EE2 + i]; int p = atomicAdd(cur2 + d, 1); eidx2[p] = i; }
}

// ---- conv1 gather (fused x1 + pool1 scatter): 32 lanes per node ----
__global__ void conv1_gather(const float* __restrict__ x, const float* __restrict__ ea,
                             const int* __restrict__ ei, const int* __restrict__ rowptr1,
                             const int* __restrict__ eidx1,
                             const float* __restrict__ w1, const float* __restrict__ b1,
                             const float* __restrict__ w2, const float* __restrict__ b2,
                             const float* __restrict__ root1, const float* __restrict__ bias1,
                             const float* __restrict__ pos, const int* __restrict__ batch,
                             const int* __restrict__ cluster1,
                             unsigned* x1pEnc, float* possum, float* ccnt, int* batch1) {
    __shared__ float sw1[50], sb1[25], sw2[25 * 32], sb2[32];
    int t = threadIdx.x;
    for (int i = t; i < 50; i += 256) sw1[i] = w1[i];
    for (int i = t; i < 25; i += 256) sb1[i] = b1[i];
    for (int i = t; i < 800; i += 256) sw2[i] = w2[i];
    for (int i = t; i < 32; i += 256) sb2[i] = b2[i];
    __syncthreads();
    int j = t & 31;
    int n = blockIdx.x * 8 + (t >> 5);
    int r0 = rowptr1[n], r1 = rowptr1[n + 1];
    float acc = 0.f;
    for (int p = r0; p < r1; p++) {
        int e = eidx1[p];
        int s = ei[e];
        float ax = ea[2 * e], ay = ea[2 * e + 1];
        float xs = x[s];
        float m = sb2[j];
#pragma unroll
        for (int k = 0; k < 25; k++) {
            float h = fmaxf(ax * sw1[k] + ay * sw1[25 + k] + sb1[k], 0.f);
            m += h * sw2[k * 32 + j];
        }
        acc += xs * m;
    }
    float deg = fmaxf((float)(r1 - r0), 1.f);
    float v = x[n] * root1[j] + acc / deg + bias1[j];
    float x1v = elu_f(v);
    int c = cluster1[n];
    atomicMax(x1pEnc + c * 32 + j, enc_f(x1v));
    if (j == 0) {
        atomicAdd(possum + 2 * c, pos[2 * n]);
        atomicAdd(possum + 2 * c + 1, pos[2 * n + 1]);
        atomicAdd(ccnt + c, 1.0f);
        atomicMax(batch1 + c, batch[n]);
    }
}

__global__ void pool1_fin(const unsigned* __restrict__ x1pEnc, const float* __restrict__ possum,
                          const float* __restrict__ ccnt, float* x1p, float* pos1, int* batch1) {
    int idx = blockIdx.x * 256 + threadIdx.x;
    if (idx >= NN1 * 32) return;
    int c = idx >> 5, j = idx & 31;
    unsigned u = x1pEnc[idx];
    x1p[idx] = (u == ENCNEG) ? 0.f : dec_f(u);
    if (j == 0) {
        float cn = fmaxf(ccnt[c], 1.0f);
        pos1[2 * c] = possum[2 * c] / cn;
        pos1[2 * c + 1] = possum[2 * c + 1] / cn;
        int b = batch1[c];
        batch1[c] = b < 0 ? 0 : (b > BB - 1 ? BB - 1 : b);
    }
}

// ---- global max |cart| over pooled edges ----
__global__ void cartmax(const float* __restrict__ pos1, const int* __restrict__ ei2, unsigned* mBits) {
    int e = blockIdx.x * 256 + threadIdx.x;
    float m = 0.f;
    if (e < EE2) {
        int r = ei2[e], c = ei2[EE2 + e];
        m = fmaxf(fabsf(pos1[2 * r] - pos1[2 * c]), fabsf(pos1[2 * r + 1] - pos1[2 * c + 1]));
    }
    for (int off = 32; off; off >>= 1) m = fmaxf(m, __shfl_xor(m, off, 64));
    if ((threadIdx.x & 63) == 0) atomicMax(mBits, __float_as_uint(m));
}

// ---- A[n, k*64+o] = sum_i x1p[n,i] * Wext[k, i*64+o]  (k=25 is b2 row) ----
__global__ void a_gemm(const float* __restrict__ x1p, const float* __restrict__ w2,
                       const float* __restrict__ b2, __hip_bfloat16* A) {
    __shared__ float Xs[64][32];
    __shared__ float Ws[32][64];
    int t = threadIdx.x;
    int n0 = blockIdx.x * 64;
    int k = blockIdx.y;
    for (int i = t; i < 64 * 32; i += 256) Xs[i / 32][i % 32] = x1p[(size_t)n0 * 32 + i];
    const float* wrow = (k < 25) ? (w2 + (size_t)k * 2048) : b2;
    for (int i = t; i < 32 * 64; i += 256) Ws[i / 64][i % 64] = wrow[i];
    __syncthreads();
    int o = t % 64, r0 = t / 64;
    float acc[16];
#pragma unroll
    for (int m2 = 0; m2 < 16; m2++) acc[m2] = 0.f;
    for (int i = 0; i < 32; i++) {
        float w = Ws[i][o];
#pragma unroll
        for (int m2 = 0; m2 < 16; m2++) acc[m2] += Xs[r0 + 4 * m2][i] * w;
    }
#pragma unroll
    for (int m2 = 0; m2 < 16; m2++) {
        int n = n0 + r0 + 4 * m2;
        A[(size_t)n * AW + k * 64 + o] = __float2bfloat16(acc[m2]);
    }
}

// ---- conv2 gather (fused x2 + pool2 scatter): 64 lanes per node ----
__global__ void conv2_gather(const __hip_bfloat16* __restrict__ A, const float* __restrict__ pos1,
                             const int* __restrict__ ei2, const int* __restrict__ rowptr2,
                             const int* __restrict__ eidx2,
                             const float* __restrict__ w1, const float* __restrict__ b1,
                             const unsigned* __restrict__ mBits,
                             const float* __restrict__ x1p, const float* __restrict__ root2,
                             const float* __restrict__ bias2,
                             const int* __restrict__ cluster2, const int* __restrict__ batch1,
                             unsigned* x2pEnc, int* batch2) {
    __shared__ float R[32 * 64];
    __shared__ float sw1[50], sb1[25];
    int t = threadIdx.x;
    for (int i = t; i < 2048; i += 256) R[i] = root2[i];
    for (int i = t; i < 50; i += 256) sw1[i] = w1[i];
    for (int i = t; i < 25; i += 256) sb1[i] = b1[i];
    __syncthreads();
    int lane = t & 63;
    int n = blockIdx.x * 4 + (t >> 6);
    int r0 = rowptr2[n], r1 = rowptr2[n + 1];
    float m = __uint_as_float(*mBits);
    float inv = 0.5f / m;
    float px = pos1[2 * n], py = pos1[2 * n + 1];
    float acc = 0.f;
    for (int p = r0; p < r1; p++) {
        int e = eidx2[p];
        int s = ei2[e];
        float cx = (pos1[2 * s] - px) * inv + 0.5f;
        float cy = (pos1[2 * s + 1] - py) * inv + 0.5f;
        float r = 0.f;
        if (lane < 25) {
            float v = cx * sw1[lane] + cy * sw1[25 + lane] + sb1[lane];
            r = v > 0.f ? v : 0.f;
        } else if (lane == 25) {
            r = 1.f;
        }
        const __hip_bfloat16* Ab = A + (size_t)s * AW + lane;
        float msg = 0.f;
#pragma unroll
        for (int k = 0; k < KA; k++) {
            float rk = __shfl(r, k, 64);
            if (rk != 0.f) msg += rk * __bfloat162float(Ab[k * 64]);
        }
        acc += msg;
    }
    float deg = fmaxf((float)(r1 - r0), 1.f);
    const float* xr = x1p + (size_t)n * 32;
    float rootacc = bias2[lane];
#pragma unroll
    for (int i = 0; i < 32; i++) rootacc += xr[i] * R[i * 64 + lane];
    float x2v = elu_f(rootacc + acc / deg);
    int c = cluster2[n];
    atomicMax(x2pEnc + c * 64 + lane, enc_f(x2v));
    if (lane == 0) atomicMax(batch2 + c, batch1[n]);
}

// ---- pool2 finalize + global mean scatter ----
__global__ void pool2_fin(const unsigned* __restrict__ x2pEnc, const int* __restrict__ batch2,
                          float* xgsum, float* gcnt) {
    int idx = blockIdx.x * 256 + threadIdx.x;
    if (idx >= NN2 * 64) return;
    int n2 = idx >> 6, o = idx & 63;
    unsigned u = x2pEnc[idx];
    float v = (u == ENCNEG) ? 0.f : dec_f(u);
    int b = batch2[n2];
    b = b < 0 ? 0 : (b > BB - 1 ? BB - 1 : b);
    atomicAdd(xgsum + (size_t)b * 64 + o, v);
    if (o == 0) atomicAdd(gcnt + b, 1.0f);
}

// ---- head: mean -> fc1+elu -> fc2 -> log_softmax ----
__global__ void head_kernel(const float* __restrict__ xgsum, const float* __restrict__ gcnt,
                            const float* __restrict__ fc1w, const float* __restrict__ fc1b,
                            const float* __restrict__ fc2w, const float* __restrict__ fc2b,
                            float* out) {
    __shared__ float xg[64];
    __shared__ float h[128];
    __shared__ float lg[NCLS];
    __shared__ float red[2];
    int b = blockIdx.x;
    int t = threadIdx.x;
    if (t < 64) xg[t] = xgsum[(size_t)b * 64 + t] / fmaxf(gcnt[b], 1.0f);
    __syncthreads();
    float acc = fc1b[t];
    for (int i = 0; i < 64; i++) acc += xg[i] * fc1w[i * 128 + t];
    h[t] = elu_f(acc);
    __syncthreads();
    if (t < NCLS) {
        float a = fc2b[t];
        for (int j = 0; j < 128; j++) a += h[j] * fc2w[j * NCLS + t];
        lg[t] = a;
    }
    __syncthreads();
    if (t == 0) {
        float mx = lg[0];
        for (int i = 1; i < NCLS; i++) mx = fmaxf(mx, lg[i]);
        float se = 0.f;
        for (int i = 0; i < NCLS; i++) se += expf(lg[i] - mx);
        red[0] = mx;
        red[1] = logf(se);
    }
    __syncthreads();
    if (t < NCLS) out[(size_t)b * NCLS + t] = lg[t] - red[0] - red[1];
}

extern "C" void kernel_launch(void* const* d_in, const int* in_sizes, int n_in,
                              void* d_out, int out_size, void* d_ws, size_t ws_size,
                              hipStream_t stream) {
    const float* x = (const float*)d_in[0];
    const float* pos = (const float*)d_in[1];
    const float* edge_attr = (const float*)d_in[2];
    const int* ei = (const int*)d_in[3];
    const int* batch = (const int*)d_in[4];
    const int* cluster1 = (const int*)d_in[5];
    const int* ei2 = (const int*)d_in[6];
    const int* cluster2 = (const int*)d_in[7];
    const float* nn1_w1 = (const float*)d_in[8];
    const float* nn1_b1 = (const float*)d_in[9];
    const float* nn1_w2 = (const float*)d_in[10];
    const float* nn1_b2 = (const float*)d_in[11];
    const float* root1 = (const float*)d_in[12];
    const float* bias1 = (const float*)d_in[13];
    const float* nn2_w1 = (const float*)d_in[14];
    const float* nn2_b1 = (const float*)d_in[15];
    const float* nn2_w2 = (const float*)d_in[16];
    const float* nn2_b2 = (const float*)d_in[17];
    const float* root2 = (const float*)d_in[18];
    const float* bias2 = (const float*)d_in[19];
    const float* fc1w = (const float*)d_in[20];
    const float* fc1b = (const float*)d_in[21];
    const float* fc2w = (const float*)d_in[22];
    const float* fc2b = (const float*)d_in[23];

    float* ws = (float*)d_ws;
    // ---- workspace layout (float units) ----
    constexpr size_t OFF_POSSUM = 0;                              // NN1*2
    constexpr size_t OFF_CCNT = OFF_POSSUM + (size_t)NN1 * 2;     // NN1
    constexpr size_t OFF_XGSUM = OFF_CCNT + NN1;                  // BB*64
    constexpr size_t OFF_GCNT = OFF_XGSUM + (size_t)BB * 64;      // BB
    constexpr size_t OFF_DEG1 = OFF_GCNT + BB;                    // NN
    constexpr size_t OFF_DEG2 = OFF_DEG1 + NN;                    // NN1
    constexpr size_t ZTOT = OFF_DEG2 + NN1;                       // end of zero region
    constexpr size_t OFF_X1PENC = ZTOT;                           // NN1*32 (uint)
    constexpr size_t OFF_X2PENC = OFF_X1PENC + (size_t)NN1 * 32;  // NN2*64 (uint)
    constexpr size_t OFF_BATCH1 = OFF_X2PENC + (size_t)NN2 * 64;  // NN1 (int)
    constexpr size_t OFF_BATCH2 = OFF_BATCH1 + NN1;               // NN2 (int)
    constexpr size_t OFF_MBITS = OFF_BATCH2 + NN2;                // 1 (uint) + pad
    constexpr size_t OFF_ROWPTR1 = OFF_MBITS + 4;                 // NN+1 (int)
    constexpr size_t OFF_ROWPTR2 = OFF_ROWPTR1 + NN + 1;          // NN1+1 (int)
    constexpr size_t OFF_CUR1 = OFF_ROWPTR2 + NN1 + 1;            // NN (int)
    constexpr size_t OFF_CUR2 = OFF_CUR1 + NN;                    // NN1 (int)
    constexpr size_t OFF_EIDX1 = OFF_CUR2 + NN1;                  // EE (int)
    constexpr size_t OFF_EIDX2 = OFF_EIDX1 + EE;                  // EE2 (int)
    constexpr size_t OFF_X1P = OFF_EIDX2 + EE2;                   // NN1*32
    constexpr size_t OFF_POS1 = OFF_X1P + (size_t)NN1 * 32;       // NN1*2
    constexpr size_t OFF_A = OFF_POS1 + (size_t)NN1 * 2;          // NN1*AW bf16 = /2 floats

    float* possum = ws + OFF_POSSUM;
    float* ccnt = ws + OFF_CCNT;
    float* xgsum = ws + OFF_XGSUM;
    float* gcnt = ws + OFF_GCNT;
    int* deg1 = (int*)(ws + OFF_DEG1);
    int* deg2 = (int*)(ws + OFF_DEG2);
    unsigned* x1pEnc = (unsigned*)(ws + OFF_X1PENC);
    unsigned* x2pEnc = (unsigned*)(ws + OFF_X2PENC);
    int* batch1 = (int*)(ws + OFF_BATCH1);
    int* batch2 = (int*)(ws + OFF_BATCH2);
    unsigned* mBits = (unsigned*)(ws + OFF_MBITS);
    int* rowptr1 = (int*)(ws + OFF_ROWPTR1);
    int* rowptr2 = (int*)(ws + OFF_ROWPTR2);
    int* cur1 = (int*)(ws + OFF_CUR1);
    int* cur2 = (int*)(ws + OFF_CUR2);
    int* eidx1 = (int*)(ws + OFF_EIDX1);
    int* eidx2 = (int*)(ws + OFF_EIDX2);
    float* x1p = ws + OFF_X1P;
    float* pos1 = ws + OFF_POS1;
    __hip_bfloat16* A = (__hip_bfloat16*)(ws + OFF_A);

    hipMemsetAsync(d_ws, 0, ZTOT * sizeof(float), stream);
    init_enc<<<2560, 256, 0, stream>>>(x1pEnc, x2pEnc, batch1, batch2, mBits);
    deg_count<<<EE / 256, 256, 0, stream>>>(ei, ei2, deg1, deg2);
    scan_two<<<2, 1024, 0, stream>>>(deg1, deg2, rowptr1, rowptr2, cur1, cur2);
    fill_csr<<<EE / 256, 256, 0, stream>>>(ei, ei2, cur1, cur2, eidx1, eidx2);
    conv1_gather<<<NN / 8, 256, 0, stream>>>(x, edge_attr, ei, rowptr1, eidx1,
                                             nn1_w1, nn1_b1, nn1_w2, nn1_b2, root1, bias1,
                                             pos, batch, cluster1,
                                             x1pEnc, possum, ccnt, batch1);
    pool1_fin<<<NN1 * 32 / 256, 256, 0, stream>>>(x1pEnc, possum, ccnt, x1p, pos1, batch1);
    cartmax<<<EE2 / 256, 256, 0, stream>>>(pos1, ei2, mBits);
    a_gemm<<<dim3(NN1 / 64, KA), 256, 0, stream>>>(x1p, nn2_w2, nn2_b2, A);
    conv2_gather<<<NN1 / 4, 256, 0, stream>>>(A, pos1, ei2, rowptr2, eidx2,
                                              nn2_w1, nn2_b1, mBits, x1p, root2, bias2,
                                              cluster2, batch1, x2pEnc, batch2);
    pool2_fin<<<NN2 * 64 / 256, 256, 0, stream>>>(x2pEnc, batch2, xgsum, gcnt);
    head_kernel<<<BB, 128, 0, stream>>>(xgsum, gcnt, fc1w, fc1b, fc2w, fc2b, (float*)d_out);
}